// Round 7
// baseline (1380.565 us; speedup 1.0000x reference)
//
#include <hip/hip_runtime.h>

#define BB 32
#define SS 256
#define EMBD 256
#define HIDD 512
#define NTAG 45
#define TPAD 48
#define NBLK 32            // worker blocks per direction (one XCD's worth)
#define APAD 520           // 512 + 8 shorts pad -> odd 16B row stride, conflict-free
#define GRID_REC 256
#define RDEPTH 4           // ring depth (skew bound is 1; need >=3, use 4)

typedef __bf16 bf16x8 __attribute__((ext_vector_type(8)));
typedef float  f32x4  __attribute__((ext_vector_type(4)));
typedef short  s16x8  __attribute__((ext_vector_type(8)));
typedef short  s16x4  __attribute__((ext_vector_type(4)));
typedef unsigned u32x4 __attribute__((ext_vector_type(4)));
typedef unsigned u32x2 __attribute__((ext_vector_type(2)));

__device__ __forceinline__ unsigned short f2bf(float x) {
  unsigned u = __builtin_bit_cast(unsigned, x);
  u = (u + 0x7fffu + ((u >> 16) & 1u)) >> 16;  // RNE
  return (unsigned short)u;
}
__device__ __forceinline__ float bf2f(unsigned short u) {
  unsigned v = ((unsigned)u) << 16; return __builtin_bit_cast(float, v);
}
__device__ __forceinline__ float ftanh(float x) {
  float e = __expf(2.f * x);
  return 1.f - 2.f / (e + 1.f);
}

// ---- cpol-controlled scalar ops (fast: sc0 = L2-coherent within XCD;
//      slow: sc0 sc1 = device-coherent) — used for the one-time XCD vote ----
__device__ __forceinline__ unsigned ld32_cpol(const unsigned* p, bool sys) {
  unsigned v;
  if (sys) asm volatile("global_load_dword %0, %1, off sc0 sc1\ns_waitcnt vmcnt(0)"
                        : "=v"(v) : "v"(p) : "memory");
  else     asm volatile("global_load_dword %0, %1, off sc0\ns_waitcnt vmcnt(0)"
                        : "=v"(v) : "v"(p) : "memory");
  return v;
}
__device__ __forceinline__ void st32_cpol(unsigned* p, unsigned v, bool sys) {
  if (sys) asm volatile("global_store_dword %0, %1, off sc0 sc1" :: "v"(p), "v"(v) : "memory");
  else     asm volatile("global_store_dword %0, %1, off sc0"     :: "v"(p), "v"(v) : "memory");
}

// ---- tagged-band poll: 16 dwordx4 loads + waitcnt in ONE asm statement
// (loads and their drain inseparable -> rule-18-safe; tag check afterwards is
// data-dependent on the outputs). 8 base pointers x offset:+-2048 keeps the
// operand count at 24 (< 30 limit).
#define POLL16(CPOL)                                                        \
  asm volatile(                                                             \
    "global_load_dwordx4 %0, %[b0], off offset:-2048 " CPOL "\n\t"          \
    "global_load_dwordx4 %1, %[b0], off offset:2048 " CPOL "\n\t"           \
    "global_load_dwordx4 %2, %[b1], off offset:-2048 " CPOL "\n\t"          \
    "global_load_dwordx4 %3, %[b1], off offset:2048 " CPOL "\n\t"           \
    "global_load_dwordx4 %4, %[b2], off offset:-2048 " CPOL "\n\t"          \
    "global_load_dwordx4 %5, %[b2], off offset:2048 " CPOL "\n\t"           \
    "global_load_dwordx4 %6, %[b3], off offset:-2048 " CPOL "\n\t"          \
    "global_load_dwordx4 %7, %[b3], off offset:2048 " CPOL "\n\t"           \
    "global_load_dwordx4 %8, %[b4], off offset:-2048 " CPOL "\n\t"          \
    "global_load_dwordx4 %9, %[b4], off offset:2048 " CPOL "\n\t"           \
    "global_load_dwordx4 %10, %[b5], off offset:-2048 " CPOL "\n\t"         \
    "global_load_dwordx4 %11, %[b5], off offset:2048 " CPOL "\n\t"          \
    "global_load_dwordx4 %12, %[b6], off offset:-2048 " CPOL "\n\t"         \
    "global_load_dwordx4 %13, %[b6], off offset:2048 " CPOL "\n\t"          \
    "global_load_dwordx4 %14, %[b7], off offset:-2048 " CPOL "\n\t"         \
    "global_load_dwordx4 %15, %[b7], off offset:2048 " CPOL "\n\t"          \
    "s_waitcnt vmcnt(0)"                                                    \
    : "=&v"(p0), "=&v"(p1), "=&v"(p2), "=&v"(p3),                           \
      "=&v"(p4), "=&v"(p5), "=&v"(p6), "=&v"(p7),                           \
      "=&v"(p8), "=&v"(p9), "=&v"(p10), "=&v"(p11),                         \
      "=&v"(p12), "=&v"(p13), "=&v"(p14), "=&v"(p15)                        \
    : [b0] "v"(bq0), [b1] "v"(bq1), [b2] "v"(bq2), [b3] "v"(bq3),           \
      [b4] "v"(bq4), [b5] "v"(bq5), [b6] "v"(bq6), [b7] "v"(bq7)            \
    : "memory")

// ---------- pack: embeddings -> bf16 [t][b][e] ----------
__global__ void k_pack_e(const int* __restrict__ x, const float* __restrict__ emb,
                         unsigned short* __restrict__ E) {
  int idx = blockIdx.x * 256 + threadIdx.x;       // exact: S*B*EMB threads
  int e = idx & 255; int bt = idx >> 8; int b = bt & 31; int t = bt >> 5;
  int tok = x[b * SS + t];
  E[idx] = f2bf(emb[(long)tok * EMBD + e]);
}

// ---------- pack weights (R0 layout) ----------
// packed row r2 = blk*64 + gate*16 + hl  <->  orig row gate*512 + blk*16 + hl
__global__ void k_pack_w(const float* __restrict__ wih_f, const float* __restrict__ whh_f,
                         const float* __restrict__ bf_,  const float* __restrict__ wih_b,
                         const float* __restrict__ whh_b, const float* __restrict__ bb_,
                         unsigned short* __restrict__ Wh, unsigned short* __restrict__ Wie,
                         float* __restrict__ Bh) {
  long idx = (long)blockIdx.x * 256 + threadIdx.x; // exact: 2*2048*768
  int k = (int)(idx % 768); long rest = idx / 768;
  int r2 = (int)(rest & 2047); int dir = (int)(rest >> 11);
  int blk = r2 >> 6, rl = r2 & 63, gate = rl >> 4, hl = rl & 15;
  int orig = gate * HIDD + blk * 16 + hl;
  const float* wih = dir ? wih_b : wih_f;
  const float* whh = dir ? whh_b : whh_f;
  if (k < HIDD) Wh[((long)(dir * 2048 + r2)) * 512 + k] = f2bf(whh[(long)orig * HIDD + k]);
  else          Wie[((long)(dir * 2048 + r2)) * 256 + (k - 512)] = f2bf(wih[(long)orig * EMBD + (k - 512)]);
  if (k == 0) {
    const float* bias = dir ? bb_ : bf_;
    Bh[dir * 2048 + r2] = bias[orig];
  }
}

// ---------- pack: lin_w -> bf16 [48][1024], lin_b -> [48] ----------
__global__ void k_pack_l(const float* __restrict__ lin_w, const float* __restrict__ lin_b,
                         unsigned short* __restrict__ LW, float* __restrict__ LB) {
  int idx = blockIdx.x * 256 + threadIdx.x;
  if (idx < TPAD * 1024) {
    int tag = idx >> 10; int c = idx & 1023;
    LW[idx] = (tag < NTAG) ? f2bf(lin_w[tag * 1024 + c]) : (unsigned short)0;
  } else if (idx < TPAD * 1024 + TPAD) {
    int tag = idx - TPAD * 1024;
    LB[tag] = (tag < NTAG) ? lin_b[tag] : 0.f;
  }
}

// ---------- input projection ----------
// Output layout: Ep[dir][blk][t][tid256][8] — per-k_rec-thread contiguous 16B
// (validated numerically in R2/R5).
__launch_bounds__(256)
__global__ void k_eproj(const unsigned short* __restrict__ E,
                        const unsigned short* __restrict__ Wie,
                        const float* __restrict__ Bh,
                        unsigned short* __restrict__ Ep) {
  __shared__ unsigned short W2[64 * 264];   // 264 = 256+8 pad
  const int bx = blockIdx.x;                // 2*32*64 = 4096
  const int tg = bx & 63, blk = (bx >> 6) & 31, dir = bx >> 11;
  const int tid = threadIdx.x;
  const int w = tid >> 6, lane = tid & 63;
  const int lm = lane & 15, quad = lane >> 4;

  { // stage Wie slice [64][256]
    const unsigned short* src = Wie + ((long)(dir * 2048 + blk * 64)) * 256;
    for (int i = 0; i < 8; ++i) {
      int c = i * 256 + tid;
      int row = c >> 5, off = c & 31;
      *(s16x8*)&W2[row * 264 + off * 8] = *(const s16x8*)&src[row * 256 + off * 8];
    }
  }
  __syncthreads();

  f32x4 acc[2][4] = {};
#pragma unroll
  for (int kk = 0; kk < 8; ++kk) {
    s16x8 av[2];
#pragma unroll
    for (int sub = 0; sub < 2; ++sub)
      av[sub] = *(const s16x8*)&E[((long)(tg * 128 + w * 32 + sub * 16 + lm)) * 256 + kk * 32 + quad * 8];
#pragma unroll
    for (int sub = 0; sub < 2; ++sub)
#pragma unroll
      for (int n = 0; n < 4; ++n) {
        s16x8 bs = *(const s16x8*)&W2[(n * 16 + lm) * 264 + kk * 32 + quad * 8];
        acc[sub][n] = __builtin_amdgcn_mfma_f32_16x16x32_bf16(
            __builtin_bit_cast(bf16x8, av[sub]), __builtin_bit_cast(bf16x8, bs), acc[sub][n], 0, 0, 0);
      }
  }
  float bh[4];
#pragma unroll
  for (int n = 0; n < 4; ++n) bh[n] = Bh[dir * 2048 + blk * 64 + n * 16 + lm];

  // C/D frag (sub,n,r): row64 = n*16+lm, t = tg*4+w, b = sub*16+quad*4+r.
  // -> consumer thread tidc = (sub*2 + (n>>1))*64 + quad*16 + lm, idx = (n&1)*4 + r
  const int t = tg * 4 + w;
#pragma unroll
  for (int sub = 0; sub < 2; ++sub)
#pragma unroll
    for (int n = 0; n < 4; ++n) {
      s16x4 pk;
#pragma unroll
      for (int r = 0; r < 4; ++r) pk[r] = (short)f2bf(acc[sub][n][r] + bh[n]);
      int tidc = (sub * 2 + (n >> 1)) * 64 + quad * 16 + lm;
      *(s16x4*)&Ep[(((long)(dir * 32 + blk) * SS + t) * 256 + tidc) * 8 + (n & 1) * 4] = pk;
    }
}

// ---------- persistent bidirectional LSTM recurrence ----------
// R5 geometry (proven 735us): 32 blocks x 256 threads per direction, one XCD
// per direction (XCC_ID vote; slow path = sc0 sc1). W_hh slice in VGPRs.
// R7 protocol — TAG-IN-DATA via a 4-slot ring (no flags, no barrier C):
//  - RING[dir][t%4][b][pair] = 8B atom {h0,h1, epoch=t+1}; producer stores ONE
//    dwordx2 sc0 per thread, fire-and-forget. A second plain 4B store keeps
//    the untagged H tensor for k_emis (never read during k_rec, never drained).
//  - Consumer wave w polls ITS OWN 32x128-col band: 16 dwordx4 + vmcnt(0)
//    fused in one asm (rule-18-safe), AND of all 32 tags/lane == t. The
//    detecting load IS the data load: store+drain+flag+poll+LD8 collapses to
//    store + one poll round trip.
//  - Ring depth 4: passing poll(t-1) bounds skew to 1 step -> writers touch
//    slots {t, t+1} % 4, never the read slot (t-1) % 4.
//  - Barriers per step: A2 (stage->MFMA), B (gates->act). B(t) orders MFMA
//    A_ls reads before stage(t+1) writes; A2(t+1) orders act(t) G_ls reads
//    before gates(t+1) writes.
//  - Ep load stays in the R0-proven slot (before the poll; drained in-spin).
__launch_bounds__(256, 1)
__global__ void k_rec(const unsigned short* __restrict__ Wh,
                      const unsigned short* __restrict__ Ep,
                      unsigned short* __restrict__ H,
                      unsigned long long* __restrict__ RING,
                      unsigned int* __restrict__ sync) {
  __shared__ unsigned short A_ls[32 * APAD];       // 33280 B: h staging, padded
  __shared__ float G_ls[32 * 66 + 4608];           // gates + pad (forces <=2 blk/CU)
  __shared__ int fast_ls;

  const int bx = blockIdx.x;
  const int role = bx & 7;
  if (role >= 2) return;                 // non-worker
  const int dir = role;
  const int blk = bx >> 3;               // 0..31
  const int tid = threadIdx.x;
  const int w = tid >> 6, lane = tid & 63;
  const int lm = lane & 15, quad = lane >> 4;
  const int mt = w >> 1, nt = w & 1;

  unsigned int* det = sync;              // [2][32]

  // ---- W_hh slice into VGPRs: rows blk*64 + nt*32 + ns*16 + lm ----
  s16x8 wb[2][16];
  {
    const unsigned short* wsrc =
        Wh + ((long)(dir * 2048 + blk * 64 + nt * 32 + lm)) * 512 + quad * 8;
#pragma unroll
    for (int ns = 0; ns < 2; ++ns)
#pragma unroll
      for (int kk = 0; kk < 16; ++kk)
        wb[ns][kk] = *(const s16x8*)&wsrc[ns * 16 * 512 + kk * 32];
  }

  // ---- protocol vote: are all 32 same-dir workers on one XCD? ----
  unsigned xcc;
  asm volatile("s_getreg_b32 %0, hwreg(HW_REG_XCC_ID)" : "=s"(xcc));
  if (tid == 0) st32_cpol(&det[dir * 32 + blk], xcc | 0x100u, true);
  if (w == 0) {
    unsigned v;
    for (;;) {
      v = (lane < 32) ? ld32_cpol(&det[dir * 32 + lane], true) : (xcc | 0x100u);
      if (__ballot(v != 0u) == ~0ull) break;
      __builtin_amdgcn_s_sleep(1);
    }
    if (lane == 0) fast_ls = (__ballot(v == (xcc | 0x100u)) == ~0ull) ? 1 : 0;
  }
  __syncthreads();
  const bool fast = (fast_ls != 0);
  __threadfence();   // one-time acquire (slow-path parity)

  const int gb = tid >> 3, hp = tid & 7;   // producer: (batch gb, hcol pair hp)
  float c0 = 0.f, c1 = 0.f;

  unsigned short* Hd = H + (long)dir * SS * BB * HIDD;
  unsigned long long* Rd = RING + (long)dir * RDEPTH * BB * 256;
  const unsigned short* Epd = Ep + (long)(dir * 32 + blk) * SS * 2048;

  // consumer band addressing: wave w, rows 2i+rsel (i=0..15), pairs psel,psel+1
  const int rsel = lane >> 5;           // 0/1
  const int psel = (lane & 31) << 1;    // even pair within band

  for (int t = 0; t < SS; ++t) {
    const int tE = (dir == 0) ? t : (SS - 1 - t);

    // ---- Ep pre-activations: issued BEFORE the poll (R0-proven slot);
    //      the poll's fused vmcnt(0) drains it while spinning ----
    s16x8 ecur = *(const s16x8*)&Epd[((long)tE * 256 + tid) * 8];

    f32x4 acc0 = {0.f, 0.f, 0.f, 0.f}, acc1 = {0.f, 0.f, 0.f, 0.f};
    if (t > 0) {
      // ---- tagged-data poll of this wave's 32x128 band ----
      {
        const int slot = (t - 1) & (RDEPTH - 1);
        const unsigned* bp =
            (const unsigned*)(Rd + ((long)slot * BB + rsel) * 256 + w * 64 + psel);
        const unsigned* bq0 = bp + 512;
        const unsigned* bq1 = bp + 1 * 2048 + 512;
        const unsigned* bq2 = bp + 2 * 2048 + 512;
        const unsigned* bq3 = bp + 3 * 2048 + 512;
        const unsigned* bq4 = bp + 4 * 2048 + 512;
        const unsigned* bq5 = bp + 5 * 2048 + 512;
        const unsigned* bq6 = bp + 6 * 2048 + 512;
        const unsigned* bq7 = bp + 7 * 2048 + 512;
        const unsigned exp_ = (unsigned)t;
        u32x4 p0, p1, p2, p3, p4, p5, p6, p7, p8, p9, p10, p11, p12, p13, p14, p15;
        for (;;) {
          if (fast) { POLL16("sc0"); } else { POLL16("sc0 sc1"); }
          unsigned ok = 1u;
          ok &= (unsigned)(p0.y == exp_)  & (unsigned)(p0.w == exp_);
          ok &= (unsigned)(p1.y == exp_)  & (unsigned)(p1.w == exp_);
          ok &= (unsigned)(p2.y == exp_)  & (unsigned)(p2.w == exp_);
          ok &= (unsigned)(p3.y == exp_)  & (unsigned)(p3.w == exp_);
          ok &= (unsigned)(p4.y == exp_)  & (unsigned)(p4.w == exp_);
          ok &= (unsigned)(p5.y == exp_)  & (unsigned)(p5.w == exp_);
          ok &= (unsigned)(p6.y == exp_)  & (unsigned)(p6.w == exp_);
          ok &= (unsigned)(p7.y == exp_)  & (unsigned)(p7.w == exp_);
          ok &= (unsigned)(p8.y == exp_)  & (unsigned)(p8.w == exp_);
          ok &= (unsigned)(p9.y == exp_)  & (unsigned)(p9.w == exp_);
          ok &= (unsigned)(p10.y == exp_) & (unsigned)(p10.w == exp_);
          ok &= (unsigned)(p11.y == exp_) & (unsigned)(p11.w == exp_);
          ok &= (unsigned)(p12.y == exp_) & (unsigned)(p12.w == exp_);
          ok &= (unsigned)(p13.y == exp_) & (unsigned)(p13.w == exp_);
          ok &= (unsigned)(p14.y == exp_) & (unsigned)(p14.w == exp_);
          ok &= (unsigned)(p15.y == exp_) & (unsigned)(p15.w == exp_);
          if (__ballot(ok != 0u) == ~0ull) break;
          __builtin_amdgcn_s_sleep(1);
        }
        // strip tags -> LDS band [row 2k+rsel][cols 128w + (lane&31)*4 ..]
        unsigned short* dbase = &A_ls[rsel * APAD + w * 128 + (lane & 31) * 4];
        *(u32x2*)(dbase + 0  * 2 * APAD) = (u32x2){p0.x,  p0.z};
        *(u32x2*)(dbase + 1  * 2 * APAD) = (u32x2){p1.x,  p1.z};
        *(u32x2*)(dbase + 2  * 2 * APAD) = (u32x2){p2.x,  p2.z};
        *(u32x2*)(dbase + 3  * 2 * APAD) = (u32x2){p3.x,  p3.z};
        *(u32x2*)(dbase + 4  * 2 * APAD) = (u32x2){p4.x,  p4.z};
        *(u32x2*)(dbase + 5  * 2 * APAD) = (u32x2){p5.x,  p5.z};
        *(u32x2*)(dbase + 6  * 2 * APAD) = (u32x2){p6.x,  p6.z};
        *(u32x2*)(dbase + 7  * 2 * APAD) = (u32x2){p7.x,  p7.z};
        *(u32x2*)(dbase + 8  * 2 * APAD) = (u32x2){p8.x,  p8.z};
        *(u32x2*)(dbase + 9  * 2 * APAD) = (u32x2){p9.x,  p9.z};
        *(u32x2*)(dbase + 10 * 2 * APAD) = (u32x2){p10.x, p10.z};
        *(u32x2*)(dbase + 11 * 2 * APAD) = (u32x2){p11.x, p11.z};
        *(u32x2*)(dbase + 12 * 2 * APAD) = (u32x2){p12.x, p12.z};
        *(u32x2*)(dbase + 13 * 2 * APAD) = (u32x2){p13.x, p13.z};
        *(u32x2*)(dbase + 14 * 2 * APAD) = (u32x2){p14.x, p14.z};
        *(u32x2*)(dbase + 15 * 2 * APAD) = (u32x2){p15.x, p15.z};
      }
      __syncthreads();   // A2: all bands in LDS before MFMA
      // ---- h @ W_hh^T : K=512, B from VGPRs ----
#pragma unroll
      for (int kk = 0; kk < 16; ++kk) {
        s16x8 av = *(const s16x8*)&A_ls[(mt * 16 + lm) * APAD + kk * 32 + quad * 8];
        acc0 = __builtin_amdgcn_mfma_f32_16x16x32_bf16(
            __builtin_bit_cast(bf16x8, av), __builtin_bit_cast(bf16x8, wb[0][kk]), acc0, 0, 0, 0);
        acc1 = __builtin_amdgcn_mfma_f32_16x16x32_bf16(
            __builtin_bit_cast(bf16x8, av), __builtin_bit_cast(bf16x8, wb[1][kk]), acc1, 0, 0, 0);
      }
    }
    // ---- gates = acc + Ep -> LDS ----
#pragma unroll
    for (int r = 0; r < 4; ++r) {
      int mm = mt * 16 + quad * 4 + r;     // C/D: row=(lane>>4)*4+reg, col=lane&15
      G_ls[mm * 66 + nt * 32 + lm]      = acc0[r] + bf2f((unsigned short)ecur[r]);
      G_ls[mm * 66 + nt * 32 + 16 + lm] = acc1[r] + bf2f((unsigned short)ecur[4 + r]);
    }
    __syncthreads();   // B
    // ---- activation + tagged ring store (no drain, no flag, no barrier C) ----
    {
      float gi0 = G_ls[gb * 66 + 0  + 2 * hp], gi1 = G_ls[gb * 66 + 0  + 2 * hp + 1];
      float gf0 = G_ls[gb * 66 + 16 + 2 * hp], gf1 = G_ls[gb * 66 + 16 + 2 * hp + 1];
      float gg0 = G_ls[gb * 66 + 32 + 2 * hp], gg1 = G_ls[gb * 66 + 32 + 2 * hp + 1];
      float go0 = G_ls[gb * 66 + 48 + 2 * hp], go1 = G_ls[gb * 66 + 48 + 2 * hp + 1];
      float si0 = 1.f / (1.f + __expf(-gi0)), si1 = 1.f / (1.f + __expf(-gi1));
      float sf0 = 1.f / (1.f + __expf(-gf0)), sf1 = 1.f / (1.f + __expf(-gf1));
      float so0 = 1.f / (1.f + __expf(-go0)), so1 = 1.f / (1.f + __expf(-go1));
      float tg0 = ftanh(gg0), tg1 = ftanh(gg1);
      c0 = sf0 * c0 + si0 * tg0;
      c1 = sf1 * c1 + si1 * tg1;
      float h0 = so0 * ftanh(c0), h1 = so1 * ftanh(c1);
      int tslot = (dir == 0) ? t : (SS - 1 - t);
      unsigned hv = (unsigned)f2bf(h0) | ((unsigned)f2bf(h1) << 16);
      // plain H store for k_emis (never read during k_rec; kernel-end flush)
      *(unsigned*)&Hd[(long)tslot * BB * HIDD + (long)gb * HIDD + blk * 16 + 2 * hp] = hv;
      // tagged ring atom {data, epoch t+1}: the store IS the handshake
      u32x2 pv; pv.x = hv; pv.y = (unsigned)(t + 1);
      unsigned long long* dst = Rd + ((long)(t & (RDEPTH - 1)) * BB + gb) * 256 + blk * 8 + hp;
      if (fast) asm volatile("global_store_dwordx2 %0, %1, off sc0"     :: "v"(dst), "v"(pv) : "memory");
      else      asm volatile("global_store_dwordx2 %0, %1, off sc0 sc1" :: "v"(dst), "v"(pv) : "memory");
    }
  }
}

// ---------- emissions: [8192,1024] x [1024,48] bf16 MFMA ----------
__launch_bounds__(256)
__global__ void k_emis(const unsigned short* __restrict__ H,
                       const unsigned short* __restrict__ LW,
                       const float* __restrict__ LB,
                       float* __restrict__ EM) {
  const int row0 = blockIdx.x * 32;
  const int tid = threadIdx.x;
  const int w = tid >> 6, lane = tid & 63;
  const int lm = lane & 15, quad = lane >> 4;
  const unsigned short* Hf = H;
  const unsigned short* Hb = H + (long)SS * BB * HIDD;

  for (int tile = w; tile < 6; tile += 4) {   // M2 x N3 tiles
    int mt = tile / 3, nt = tile % 3;
    int arow = row0 + mt * 16 + lm;
    int nrow = nt * 16 + lm;
    f32x4 acc = {0.f, 0.f, 0.f, 0.f};
#pragma unroll 4
    for (int kk = 0; kk < 32; ++kk) {
      int k0 = kk * 32 + quad * 8;
      s16x8 asv = (k0 < HIDD) ? *(const s16x8*)&Hf[(long)arow * HIDD + k0]
                              : *(const s16x8*)&Hb[(long)arow * HIDD + (k0 - HIDD)];
      s16x8 bsv = *(const s16x8*)&LW[nrow * 1024 + k0];
      acc = __builtin_amdgcn_mfma_f32_16x16x32_bf16(
          __builtin_bit_cast(bf16x8, asv), __builtin_bit_cast(bf16x8, bsv), acc, 0, 0, 0);
    }
    float bias = LB[nrow];
#pragma unroll
    for (int r = 0; r < 4; ++r) {
      int mm = row0 + mt * 16 + quad * 4 + r;
      EM[(long)mm * TPAD + nrow] = acc[r] + bias;
    }
  }
}

// ---------- CRF: one wave per chain, scaled (linear-space) forward ----------
__global__ void k_crf(const int* __restrict__ tags, const float* __restrict__ start_t,
                      const float* __restrict__ end_t, const float* __restrict__ trans,
                      const float* __restrict__ EM, float* __restrict__ chain) {
  __shared__ float T_ls[NTAG * TPAD];
  __shared__ float ET[48 * 48 + 16];
  __shared__ float P_ls[64];
  const int b = blockIdx.x;
  const int lane = threadIdx.x;   // 64 threads, single wave
  const int j = lane;

  for (int i = lane; i < NTAG * NTAG; i += 64)
    T_ls[(i / NTAG) * TPAD + (i % NTAG)] = trans[i];
  for (int i = lane; i < 48 * 48 + 16; i += 64) ET[i] = 0.f;
  __syncthreads();

  float Mj = -1e30f;
  if (j < NTAG) {
    for (int i = 0; i < NTAG; ++i) Mj = fmaxf(Mj, T_ls[i * TPAD + j]);
    for (int i = 0; i < NTAG; ++i) ET[i * 48 + j] = __expf(T_ls[i * TPAD + j] - Mj);
  }
  __syncthreads();

  float et[48];
#pragma unroll
  for (int i = 0; i < 48; ++i) et[i] = ET[i * 48 + j];

  float part = 0.f;
  for (int t = lane; t < SS; t += 64) {
    int tg = tags[b * SS + t];
    part += EM[((long)t * BB + b) * TPAD + tg];
    if (t + 1 < SS) part += T_ls[tg * TPAD + tags[b * SS + t + 1]];
    if (t == 0)      part += start_t[tg];
    if (t == SS - 1) part += end_t[tg];
  }
  for (int off = 32; off; off >>= 1) part += __shfl_down(part, off);
  float score = __shfl(part, 0);

  float alpha = (j < NTAG) ? (start_t[j] + EM[(long)b * TPAD + j]) : -1e30f;
  float e_next = (j < NTAG) ? EM[((long)BB + b) * TPAD + j] : 0.f;
  for (int t = 1; t < SS; ++t) {
    float e_cur = e_next;
    if (t < SS - 1) e_next = (j < NTAG) ? EM[((long)(t + 1) * BB + b) * TPAD + j] : 0.f;
    float am = alpha;
#pragma unroll
    for (int off = 32; off; off >>= 1) am = fmaxf(am, __shfl_xor(am, off));
    float p = __expf(alpha - am);
    P_ls[lane] = p;
    __builtin_amdgcn_wave_barrier();
    float s0 = 0.f, s1 = 0.f, s2 = 0.f, s3 = 0.f;
#pragma unroll
    for (int i0 = 0; i0 < 48; i0 += 4) {
      f32x4 pv = *(const f32x4*)&P_ls[i0];
      s0 += pv.x * et[i0];
      s1 += pv.y * et[i0 + 1];
      s2 += pv.z * et[i0 + 2];
      s3 += pv.w * et[i0 + 3];
    }
    __builtin_amdgcn_wave_barrier();
    float s = (s0 + s1) + (s2 + s3);
    float na = am + Mj + __logf(s) + e_cur;
    alpha = (j < NTAG) ? na : -1e30f;
  }
  float v = (j < NTAG) ? (alpha + end_t[j]) : -1e30f;
  float mx = v;
  for (int off = 32; off; off >>= 1) mx = fmaxf(mx, __shfl_xor(mx, off));
  float s = __expf(v - mx);
  for (int off = 32; off; off >>= 1) s += __shfl_xor(s, off);
  if (lane == 0) chain[b] = score - (mx + __logf(s));
}

__global__ void k_fin(const float* __restrict__ chain, float* __restrict__ out) {
  int lane = threadIdx.x;
  float v = (lane < BB) ? chain[lane] : 0.f;
  for (int off = 32; off; off >>= 1) v += __shfl_xor(v, off);
  if (lane == 0) out[0] = -v / (float)BB;
}

extern "C" void kernel_launch(void* const* d_in, const int* in_sizes, int n_in,
                              void* d_out, int out_size, void* d_ws, size_t ws_size,
                              hipStream_t stream) {
  const int*   x      = (const int*)d_in[0];
  const int*   tags   = (const int*)d_in[1];
  const float* emb    = (const float*)d_in[2];
  const float* wih_f  = (const float*)d_in[3];
  const float* whh_f  = (const float*)d_in[4];
  const float* b_f    = (const float*)d_in[5];
  const float* wih_b  = (const float*)d_in[6];
  const float* whh_b  = (const float*)d_in[7];
  const float* b_b    = (const float*)d_in[8];
  const float* lin_w  = (const float*)d_in[9];
  const float* lin_b  = (const float*)d_in[10];
  const float* start_t= (const float*)d_in[11];
  const float* end_t  = (const float*)d_in[12];
  const float* trans  = (const float*)d_in[13];

  char* ws = (char*)d_ws;
  size_t off = 0;
  auto alloc = [&](size_t bytes) {
    void* p = ws + off; off = (off + bytes + 255) & ~(size_t)255; return p;
  };
  size_t sync_bytes = 64 * 4;                                                    // det only
  unsigned int*   sync = (unsigned int*) alloc(sync_bytes);
  unsigned short* E   = (unsigned short*)alloc((size_t)SS * BB * EMBD * 2);      // 4 MB
  unsigned short* Wh  = (unsigned short*)alloc((size_t)2 * 2048 * 512 * 2);      // 4 MB
  unsigned short* Wie = (unsigned short*)alloc((size_t)2 * 2048 * 256 * 2);      // 2 MB
  float*          Bh  = (float*)         alloc((size_t)2 * 2048 * 4);
  unsigned short* Ep  = (unsigned short*)alloc((size_t)2 * 32 * SS * 2048 * 2);  // 67 MB
  unsigned short* H   = (unsigned short*)alloc((size_t)2 * SS * BB * HIDD * 2);  // 16 MB
  unsigned short* LW  = (unsigned short*)alloc((size_t)TPAD * 1024 * 2);
  float*          LB  = (float*)         alloc((size_t)TPAD * 4);
  float*          EM  = (float*)         alloc((size_t)SS * BB * TPAD * 4);      // 1.5 MB
  float*          chain = (float*)       alloc((size_t)BB * 4);

  // 2 MB tagged ring ALIASED over E (dead after k_eproj) -> ws stays at the
  // R5-proven ~96 MB envelope. Memset ordered AFTER k_eproj, BEFORE k_rec.
  unsigned long long* RING = (unsigned long long*)E;
  size_t ring_bytes = (size_t)2 * RDEPTH * BB * 256 * 8;

  hipMemsetAsync(sync, 0, sync_bytes, stream);
  k_pack_e<<<dim3((SS * BB * EMBD) / 256), dim3(256), 0, stream>>>(x, emb, E);
  k_pack_w<<<dim3((2 * 2048 * 768) / 256), dim3(256), 0, stream>>>(
      wih_f, whh_f, b_f, wih_b, whh_b, b_b, Wh, Wie, Bh);
  k_pack_l<<<dim3((TPAD * 1024 + TPAD + 255) / 256), dim3(256), 0, stream>>>(
      lin_w, lin_b, LW, LB);
  k_eproj<<<dim3(4096), dim3(256), 0, stream>>>(E, Wie, Bh, Ep);
  hipMemsetAsync(RING, 0, ring_bytes, stream);   // clear epoch tags (after eproj!)

  void* kargs[] = {&Wh, &Ep, &H, &RING, &sync};
  hipLaunchCooperativeKernel((const void*)k_rec, dim3(GRID_REC), dim3(256), kargs, 0, stream);

  k_emis<<<dim3((SS * BB) / 32), dim3(256), 0, stream>>>(H, LW, LB, EM);
  k_crf<<<dim3(BB), dim3(64), 0, stream>>>(tags, start_t, end_t, trans, EM, chain);
  k_fin<<<dim3(1), dim3(64), 0, stream>>>(chain, (float*)d_out);
}

// Round 8
// 1062.870 us; speedup vs baseline: 1.2989x; 1.2989x over previous
//
#include <hip/hip_runtime.h>

#define BB 32
#define SS 256
#define EMBD 256
#define HIDD 512
#define NTAG 45
#define TPAD 48
#define NBLK 32            // worker blocks per direction (one XCD's worth)
#define APAD 520           // 512 + 8 shorts pad -> odd 16B row stride, conflict-free
#define GRID_REC 256

// fused pack-kernel block ranges
#define PB_E 8192                      // (SS*BB*EMBD)/256
#define PB_W 12288                     // (2*2048*768)/256
#define PB_L 193                       // ceil((TPAD*1024+TPAD)/256)
#define PB_ALL (PB_E + PB_W + PB_L)

typedef __bf16 bf16x8 __attribute__((ext_vector_type(8)));
typedef float  f32x4  __attribute__((ext_vector_type(4)));
typedef short  s16x8  __attribute__((ext_vector_type(8)));
typedef short  s16x4  __attribute__((ext_vector_type(4)));

__device__ __forceinline__ unsigned short f2bf(float x) {
  unsigned u = __builtin_bit_cast(unsigned, x);
  u = (u + 0x7fffu + ((u >> 16) & 1u)) >> 16;  // RNE
  return (unsigned short)u;
}
__device__ __forceinline__ float bf2f(unsigned short u) {
  unsigned v = ((unsigned)u) << 16; return __builtin_bit_cast(float, v);
}
__device__ __forceinline__ float ftanh(float x) {
  float e = __expf(2.f * x);
  return 1.f - 2.f / (e + 1.f);
}

// ---- cpol-controlled scalar ops (fast: sc0 = L2-coherent within XCD;
//      slow: sc0 sc1 = IF$ device-coherent) ----
__device__ __forceinline__ unsigned ld32_cpol(const unsigned* p, bool sys) {
  unsigned v;
  if (sys) asm volatile("global_load_dword %0, %1, off sc0 sc1\ns_waitcnt vmcnt(0)"
                        : "=v"(v) : "v"(p) : "memory");
  else     asm volatile("global_load_dword %0, %1, off sc0\ns_waitcnt vmcnt(0)"
                        : "=v"(v) : "v"(p) : "memory");
  return v;
}
__device__ __forceinline__ void st32_cpol(unsigned* p, unsigned v, bool sys) {
  if (sys) asm volatile("global_store_dword %0, %1, off sc0 sc1" :: "v"(p), "v"(v) : "memory");
  else     asm volatile("global_store_dword %0, %1, off sc0"     :: "v"(p), "v"(v) : "memory");
}

#define LD8(CPOL)                                                           \
  asm volatile("global_load_dwordx4 %0, %[q0], off " CPOL "\n\t"            \
               "global_load_dwordx4 %1, %[q1], off " CPOL "\n\t"            \
               "global_load_dwordx4 %2, %[q2], off " CPOL "\n\t"            \
               "global_load_dwordx4 %3, %[q3], off " CPOL "\n\t"            \
               "global_load_dwordx4 %4, %[q4], off " CPOL "\n\t"            \
               "global_load_dwordx4 %5, %[q5], off " CPOL "\n\t"            \
               "global_load_dwordx4 %6, %[q6], off " CPOL "\n\t"            \
               "global_load_dwordx4 %7, %[q7], off " CPOL "\n\t"            \
               "s_waitcnt vmcnt(0)"                                         \
               : "=&v"(v0), "=&v"(v1), "=&v"(v2), "=&v"(v3),                \
                 "=&v"(v4), "=&v"(v5), "=&v"(v6), "=&v"(v7)                 \
               : [q0] "v"(p), [q1] "v"(p + 2048), [q2] "v"(p + 4096),       \
                 [q3] "v"(p + 6144), [q4] "v"(p + 8192), [q5] "v"(p + 10240),\
                 [q6] "v"(p + 12288), [q7] "v"(p + 14336)                   \
               : "memory")

// ---------- fused pack: E, weights, linear (block-range dispatch) ----------
// Indexing for each branch is IDENTICAL to the R5 kernels; only the launch
// count changes (3 dispatches -> 1).
__global__ void k_pack_all(const int* __restrict__ x, const float* __restrict__ emb,
                           unsigned short* __restrict__ E,
                           const float* __restrict__ wih_f, const float* __restrict__ whh_f,
                           const float* __restrict__ bf_,  const float* __restrict__ wih_b,
                           const float* __restrict__ whh_b, const float* __restrict__ bb_,
                           unsigned short* __restrict__ Wh, unsigned short* __restrict__ Wie,
                           float* __restrict__ Bh,
                           const float* __restrict__ lin_w, const float* __restrict__ lin_b,
                           unsigned short* __restrict__ LW, float* __restrict__ LB) {
  const int bx = blockIdx.x;
  if (bx < PB_E) {
    // ---- embeddings -> bf16 [t][b][e] ----
    int idx = bx * 256 + threadIdx.x;             // exact: S*B*EMB threads
    int e = idx & 255; int bt = idx >> 8; int b = bt & 31; int t = bt >> 5;
    int tok = x[b * SS + t];
    E[idx] = f2bf(emb[(long)tok * EMBD + e]);
  } else if (bx < PB_E + PB_W) {
    // ---- weights: r2 = blk*64 + gate*16 + hl <-> orig gate*512 + blk*16 + hl ----
    long idx = (long)(bx - PB_E) * 256 + threadIdx.x;  // exact: 2*2048*768
    int k = (int)(idx % 768); long rest = idx / 768;
    int r2 = (int)(rest & 2047); int dir = (int)(rest >> 11);
    int blk = r2 >> 6, rl = r2 & 63, gate = rl >> 4, hl = rl & 15;
    int orig = gate * HIDD + blk * 16 + hl;
    const float* wih = dir ? wih_b : wih_f;
    const float* whh = dir ? whh_b : whh_f;
    if (k < HIDD) Wh[((long)(dir * 2048 + r2)) * 512 + k] = f2bf(whh[(long)orig * HIDD + k]);
    else          Wie[((long)(dir * 2048 + r2)) * 256 + (k - 512)] = f2bf(wih[(long)orig * EMBD + (k - 512)]);
    if (k == 0) {
      const float* bias = dir ? bb_ : bf_;
      Bh[dir * 2048 + r2] = bias[orig];
    }
  } else {
    // ---- lin_w -> bf16 [48][1024], lin_b -> [48] ----
    int idx = (bx - PB_E - PB_W) * 256 + threadIdx.x;
    if (idx < TPAD * 1024) {
      int tag = idx >> 10; int c = idx & 1023;
      LW[idx] = (tag < NTAG) ? f2bf(lin_w[tag * 1024 + c]) : (unsigned short)0;
    } else if (idx < TPAD * 1024 + TPAD) {
      int tag = idx - TPAD * 1024;
      LB[tag] = (tag < NTAG) ? lin_b[tag] : 0.f;
    }
  }
}

// ---------- input projection ----------
// Output layout: Ep[dir][blk][t][tid256][8] — per-k_rec-thread contiguous 16B
// (validated numerically in R2/R5).
__launch_bounds__(256)
__global__ void k_eproj(const unsigned short* __restrict__ E,
                        const unsigned short* __restrict__ Wie,
                        const float* __restrict__ Bh,
                        unsigned short* __restrict__ Ep) {
  __shared__ unsigned short W2[64 * 264];   // 264 = 256+8 pad
  const int bx = blockIdx.x;                // 2*32*64 = 4096
  const int tg = bx & 63, blk = (bx >> 6) & 31, dir = bx >> 11;
  const int tid = threadIdx.x;
  const int w = tid >> 6, lane = tid & 63;
  const int lm = lane & 15, quad = lane >> 4;

  { // stage Wie slice [64][256]
    const unsigned short* src = Wie + ((long)(dir * 2048 + blk * 64)) * 256;
    for (int i = 0; i < 8; ++i) {
      int c = i * 256 + tid;             // chunk: row = c>>5, off = c&31
      int row = c >> 5, off = c & 31;
      *(s16x8*)&W2[row * 264 + off * 8] = *(const s16x8*)&src[row * 256 + off * 8];
    }
  }
  __syncthreads();

  f32x4 acc[2][4] = {};
#pragma unroll
  for (int kk = 0; kk < 8; ++kk) {
    s16x8 av[2];
#pragma unroll
    for (int sub = 0; sub < 2; ++sub)
      av[sub] = *(const s16x8*)&E[((long)(tg * 128 + w * 32 + sub * 16 + lm)) * 256 + kk * 32 + quad * 8];
#pragma unroll
    for (int sub = 0; sub < 2; ++sub)
#pragma unroll
      for (int n = 0; n < 4; ++n) {
        s16x8 bs = *(const s16x8*)&W2[(n * 16 + lm) * 264 + kk * 32 + quad * 8];
        acc[sub][n] = __builtin_amdgcn_mfma_f32_16x16x32_bf16(
            __builtin_bit_cast(bf16x8, av[sub]), __builtin_bit_cast(bf16x8, bs), acc[sub][n], 0, 0, 0);
      }
  }
  float bh[4];
#pragma unroll
  for (int n = 0; n < 4; ++n) bh[n] = Bh[dir * 2048 + blk * 64 + n * 16 + lm];

  // C/D frag (sub,n,r): row64 = n*16+lm, t = tg*4+w, b = sub*16+quad*4+r.
  // -> consumer thread tidc = (sub*2 + (n>>1))*64 + quad*16 + lm, idx = (n&1)*4 + r
  const int t = tg * 4 + w;
#pragma unroll
  for (int sub = 0; sub < 2; ++sub)
#pragma unroll
    for (int n = 0; n < 4; ++n) {
      s16x4 pk;
#pragma unroll
      for (int r = 0; r < 4; ++r) pk[r] = (short)f2bf(acc[sub][n][r] + bh[n]);
      int tidc = (sub * 2 + (n >> 1)) * 64 + quad * 16 + lm;
      *(s16x4*)&Ep[(((long)(dir * 32 + blk) * SS + t) * 256 + tidc) * 8 + (n & 1) * 4] = pk;
    }
}

// ---------- persistent bidirectional LSTM recurrence ----------
// EXACT R5 protocol (proven 735us): 32 blocks x 256 threads per direction
// (bx%8==dir -> one XCD per direction, XCC_ID vote; slow path = sc0 sc1);
// wave0-only flag poll + barrier A; block-wide LD8 h staging; barrier A2;
// MFMA (W_hh slice in VGPRs); gates->LDS; barrier B; activation; h store;
// barrier C (drains vmcnt) + tid0 flag store. Ep as ONE contiguous 16B load
// issued before the poll (drained while spinning); ftanh.
// R1-R7 lesson (all regressed): any byte added to the producer drained path
// or load added to the consumer poll path costs full latency on the chain;
// this skeleton has the minimum of both. Do not rearrange.
__launch_bounds__(256, 1)
__global__ void k_rec(const unsigned short* __restrict__ Wh,
                      const unsigned short* __restrict__ Ep,
                      unsigned short* __restrict__ H,
                      unsigned int* __restrict__ sync) {
  __shared__ unsigned short A_ls[32 * APAD];       // 33280 B: h staging, padded
  __shared__ float G_ls[32 * 66 + 4608];           // gates + pad (forces <=2 blk/CU)
  __shared__ int fast_ls;

  const int bx = blockIdx.x;
  const int role = bx & 7;
  if (role >= 2) return;                 // non-worker
  const int dir = role;
  const int blk = bx >> 3;               // 0..31
  const int tid = threadIdx.x;
  const int w = tid >> 6, lane = tid & 63;
  const int lm = lane & 15, quad = lane >> 4;
  const int mt = w >> 1, nt = w & 1;

  unsigned int* det   = sync;                          // [2][32]
  unsigned int* flags = sync + 64;                     // [2][256][32]

  // ---- W_hh slice into VGPRs: rows blk*64 + nt*32 + ns*16 + lm ----
  s16x8 wb[2][16];
  {
    const unsigned short* wsrc =
        Wh + ((long)(dir * 2048 + blk * 64 + nt * 32 + lm)) * 512 + quad * 8;
#pragma unroll
    for (int ns = 0; ns < 2; ++ns)
#pragma unroll
      for (int kk = 0; kk < 16; ++kk)
        wb[ns][kk] = *(const s16x8*)&wsrc[ns * 16 * 512 + kk * 32];
  }

  // ---- protocol vote: are all 32 same-dir workers on one XCD? ----
  unsigned xcc;
  asm volatile("s_getreg_b32 %0, hwreg(HW_REG_XCC_ID)" : "=s"(xcc));
  if (tid == 0) st32_cpol(&det[dir * 32 + blk], xcc | 0x100u, true);
  if (w == 0) {
    unsigned v;
    for (;;) {
      v = (lane < 32) ? ld32_cpol(&det[dir * 32 + lane], true) : (xcc | 0x100u);
      if (__ballot(v != 0u) == ~0ull) break;
      __builtin_amdgcn_s_sleep(1);
    }
    if (lane == 0) fast_ls = (__ballot(v == (xcc | 0x100u)) == ~0ull) ? 1 : 0;
  }
  __syncthreads();
  const bool fast = (fast_ls != 0);
  __threadfence();   // one-time acquire (slow-path parity)

  const int gb = tid >> 3, hp = tid & 7;   // gate assembly: (batch, hcol pair)
  float c0 = 0.f, c1 = 0.f;

  unsigned short* Hd = H + (long)dir * SS * BB * HIDD;
  unsigned int* flagd = flags + dir * SS * NBLK;
  const unsigned short* Epd = Ep + (long)(dir * 32 + blk) * SS * 2048;

  for (int t = 0; t < SS; ++t) {
    const int tE = (dir == 0) ? t : (SS - 1 - t);

    // ---- Ep gate pre-activations (independent of h): issue early, R0 slot.
    //      One contiguous 16B load; latency hides under the poll/barrier A. ----
    s16x8 ecur = *(const s16x8*)&Epd[((long)tE * 256 + tid) * 8];

    f32x4 acc0 = {0.f, 0.f, 0.f, 0.f}, acc1 = {0.f, 0.f, 0.f, 0.f};
    if (t > 0) {
      // ---- wait for all same-dir blocks' h from step t-1 (wave0 only) ----
      if (w == 0) {
        const unsigned int* fl = flagd + (long)(t - 1) * NBLK;
        for (;;) {
          unsigned f = (lane < 32) ? ld32_cpol(&fl[lane], !fast) : 1u;
          if (__ballot(f != 0u) == ~0ull) break;
          __builtin_amdgcn_s_sleep(1);
        }
      }
      __syncthreads();   // A
      // ---- stage h[hslot] (32x512 bf16) into padded LDS ----
      {
        const int hslot = (dir == 0) ? (t - 1) : (SS - t);
        const unsigned short* p = Hd + (long)hslot * BB * HIDD + w * 512 + lane * 8;
        s16x8 v0, v1, v2, v3, v4, v5, v6, v7;
        if (fast) { LD8("sc0"); } else { LD8("sc0 sc1"); }
        unsigned short* d = &A_ls[w * APAD + lane * 8];
        *(s16x8*)(d + 0 * 2080) = v0; *(s16x8*)(d + 1 * 2080) = v1;
        *(s16x8*)(d + 2 * 2080) = v2; *(s16x8*)(d + 3 * 2080) = v3;
        *(s16x8*)(d + 4 * 2080) = v4; *(s16x8*)(d + 5 * 2080) = v5;
        *(s16x8*)(d + 6 * 2080) = v6; *(s16x8*)(d + 7 * 2080) = v7;
      }
      __syncthreads();   // A2
      // ---- h @ W_hh^T : K=512, B from VGPRs ----
#pragma unroll
      for (int kk = 0; kk < 16; ++kk) {
        s16x8 av = *(const s16x8*)&A_ls[(mt * 16 + lm) * APAD + kk * 32 + quad * 8];
        acc0 = __builtin_amdgcn_mfma_f32_16x16x32_bf16(
            __builtin_bit_cast(bf16x8, av), __builtin_bit_cast(bf16x8, wb[0][kk]), acc0, 0, 0, 0);
        acc1 = __builtin_amdgcn_mfma_f32_16x16x32_bf16(
            __builtin_bit_cast(bf16x8, av), __builtin_bit_cast(bf16x8, wb[1][kk]), acc1, 0, 0, 0);
      }
    }
    // ---- gates = acc + Ep -> LDS ----
#pragma unroll
    for (int r = 0; r < 4; ++r) {
      int mm = mt * 16 + quad * 4 + r;     // C/D: row=(lane>>4)*4+reg, col=lane&15
      G_ls[mm * 66 + nt * 32 + lm]      = acc0[r] + bf2f((unsigned short)ecur[r]);
      G_ls[mm * 66 + nt * 32 + 16 + lm] = acc1[r] + bf2f((unsigned short)ecur[4 + r]);
    }
    __syncthreads();   // B
    // ---- activation: thread -> (batch gb, hcols 2hp, 2hp+1) ----
    {
      float gi0 = G_ls[gb * 66 + 0  + 2 * hp], gi1 = G_ls[gb * 66 + 0  + 2 * hp + 1];
      float gf0 = G_ls[gb * 66 + 16 + 2 * hp], gf1 = G_ls[gb * 66 + 16 + 2 * hp + 1];
      float gg0 = G_ls[gb * 66 + 32 + 2 * hp], gg1 = G_ls[gb * 66 + 32 + 2 * hp + 1];
      float go0 = G_ls[gb * 66 + 48 + 2 * hp], go1 = G_ls[gb * 66 + 48 + 2 * hp + 1];
      float si0 = 1.f / (1.f + __expf(-gi0)), si1 = 1.f / (1.f + __expf(-gi1));
      float sf0 = 1.f / (1.f + __expf(-gf0)), sf1 = 1.f / (1.f + __expf(-gf1));
      float so0 = 1.f / (1.f + __expf(-go0)), so1 = 1.f / (1.f + __expf(-go1));
      float tg0 = ftanh(gg0), tg1 = ftanh(gg1);
      c0 = sf0 * c0 + si0 * tg0;
      c1 = sf1 * c1 + si1 * tg1;
      float h0 = so0 * ftanh(c0), h1 = so1 * ftanh(c1);
      int tslot = (dir == 0) ? t : (SS - 1 - t);
      unsigned hv = (unsigned)f2bf(h0) | ((unsigned)f2bf(h1) << 16);
      st32_cpol((unsigned*)&Hd[(long)tslot * BB * HIDD + (long)gb * HIDD + blk * 16 + 2 * hp],
                hv, !fast);
    }
    __syncthreads();   // C: all waves drained vmcnt -> h visible at protocol point
    if (t < SS - 1 && tid == 0)
      st32_cpol(&flagd[(long)t * NBLK + blk], 1u, !fast);
  }
}

// ---------- emissions: [8192,1024] x [1024,48] bf16 MFMA ----------
__launch_bounds__(256)
__global__ void k_emis(const unsigned short* __restrict__ H,
                       const unsigned short* __restrict__ LW,
                       const float* __restrict__ LB,
                       float* __restrict__ EM) {
  const int row0 = blockIdx.x * 32;
  const int tid = threadIdx.x;
  const int w = tid >> 6, lane = tid & 63;
  const int lm = lane & 15, quad = lane >> 4;
  const unsigned short* Hf = H;
  const unsigned short* Hb = H + (long)SS * BB * HIDD;

  for (int tile = w; tile < 6; tile += 4) {   // M2 x N3 tiles
    int mt = tile / 3, nt = tile % 3;
    int arow = row0 + mt * 16 + lm;
    int nrow = nt * 16 + lm;
    f32x4 acc = {0.f, 0.f, 0.f, 0.f};
#pragma unroll 4
    for (int kk = 0; kk < 32; ++kk) {
      int k0 = kk * 32 + quad * 8;
      s16x8 asv = (k0 < HIDD) ? *(const s16x8*)&Hf[(long)arow * HIDD + k0]
                              : *(const s16x8*)&Hb[(long)arow * HIDD + (k0 - HIDD)];
      s16x8 bsv = *(const s16x8*)&LW[nrow * 1024 + k0];
      acc = __builtin_amdgcn_mfma_f32_16x16x32_bf16(
          __builtin_bit_cast(bf16x8, asv), __builtin_bit_cast(bf16x8, bsv), acc, 0, 0, 0);
    }
    float bias = LB[nrow];
#pragma unroll
    for (int r = 0; r < 4; ++r) {
      int mm = row0 + mt * 16 + quad * 4 + r;
      EM[(long)mm * TPAD + nrow] = acc[r] + bias;
    }
  }
}

// ---------- CRF: one wave per chain, scaled (linear-space) forward ----------
__global__ void k_crf(const int* __restrict__ tags, const float* __restrict__ start_t,
                      const float* __restrict__ end_t, const float* __restrict__ trans,
                      const float* __restrict__ EM, float* __restrict__ chain) {
  __shared__ float T_ls[NTAG * TPAD];
  __shared__ float ET[48 * 48 + 16];
  __shared__ float P_ls[64];
  const int b = blockIdx.x;
  const int lane = threadIdx.x;   // 64 threads, single wave
  const int j = lane;

  for (int i = lane; i < NTAG * NTAG; i += 64)
    T_ls[(i / NTAG) * TPAD + (i % NTAG)] = trans[i];
  for (int i = lane; i < 48 * 48 + 16; i += 64) ET[i] = 0.f;
  __syncthreads();

  float Mj = -1e30f;
  if (j < NTAG) {
    for (int i = 0; i < NTAG; ++i) Mj = fmaxf(Mj, T_ls[i * TPAD + j]);
    for (int i = 0; i < NTAG; ++i) ET[i * 48 + j] = __expf(T_ls[i * TPAD + j] - Mj);
  }
  __syncthreads();

  float et[48];
#pragma unroll
  for (int i = 0; i < 48; ++i) et[i] = ET[i * 48 + j];

  float part = 0.f;
  for (int t = lane; t < SS; t += 64) {
    int tg = tags[b * SS + t];
    part += EM[((long)t * BB + b) * TPAD + tg];
    if (t + 1 < SS) part += T_ls[tg * TPAD + tags[b * SS + t + 1]];
    if (t == 0)      part += start_t[tg];
    if (t == SS - 1) part += end_t[tg];
  }
  for (int off = 32; off; off >>= 1) part += __shfl_down(part, off);
  float score = __shfl(part, 0);

  float alpha = (j < NTAG) ? (start_t[j] + EM[(long)b * TPAD + j]) : -1e30f;
  float e_next = (j < NTAG) ? EM[((long)BB + b) * TPAD + j] : 0.f;
  for (int t = 1; t < SS; ++t) {
    float e_cur = e_next;
    if (t < SS - 1) e_next = (j < NTAG) ? EM[((long)(t + 1) * BB + b) * TPAD + j] : 0.f;
    float am = alpha;
#pragma unroll
    for (int off = 32; off; off >>= 1) am = fmaxf(am, __shfl_xor(am, off));
    float p = __expf(alpha - am);
    P_ls[lane] = p;
    __builtin_amdgcn_wave_barrier();
    float s0 = 0.f, s1 = 0.f, s2 = 0.f, s3 = 0.f;
#pragma unroll
    for (int i0 = 0; i0 < 48; i0 += 4) {
      f32x4 pv = *(const f32x4*)&P_ls[i0];
      s0 += pv.x * et[i0];
      s1 += pv.y * et[i0 + 1];
      s2 += pv.z * et[i0 + 2];
      s3 += pv.w * et[i0 + 3];
    }
    __builtin_amdgcn_wave_barrier();
    float s = (s0 + s1) + (s2 + s3);
    float na = am + Mj + __logf(s) + e_cur;
    alpha = (j < NTAG) ? na : -1e30f;
  }
  float v = (j < NTAG) ? (alpha + end_t[j]) : -1e30f;
  float mx = v;
  for (int off = 32; off; off >>= 1) mx = fmaxf(mx, __shfl_xor(mx, off));
  float s = __expf(v - mx);
  for (int off = 32; off; off >>= 1) s += __shfl_xor(s, off);
  if (lane == 0) chain[b] = score - (mx + __logf(s));
}

__global__ void k_fin(const float* __restrict__ chain, float* __restrict__ out) {
  int lane = threadIdx.x;
  float v = (lane < BB) ? chain[lane] : 0.f;
  for (int off = 32; off; off >>= 1) v += __shfl_xor(v, off);
  if (lane == 0) out[0] = -v / (float)BB;
}

extern "C" void kernel_launch(void* const* d_in, const int* in_sizes, int n_in,
                              void* d_out, int out_size, void* d_ws, size_t ws_size,
                              hipStream_t stream) {
  const int*   x      = (const int*)d_in[0];
  const int*   tags   = (const int*)d_in[1];
  const float* emb    = (const float*)d_in[2];
  const float* wih_f  = (const float*)d_in[3];
  const float* whh_f  = (const float*)d_in[4];
  const float* b_f    = (const float*)d_in[5];
  const float* wih_b  = (const float*)d_in[6];
  const float* whh_b  = (const float*)d_in[7];
  const float* b_b    = (const float*)d_in[8];
  const float* lin_w  = (const float*)d_in[9];
  const float* lin_b  = (const float*)d_in[10];
  const float* start_t= (const float*)d_in[11];
  const float* end_t  = (const float*)d_in[12];
  const float* trans  = (const float*)d_in[13];

  char* ws = (char*)d_ws;
  size_t off = 0;
  auto alloc = [&](size_t bytes) {
    void* p = ws + off; off = (off + bytes + 255) & ~(size_t)255; return p;
  };
  size_t sync_bytes = (64 + 2 * SS * NBLK) * 4;                                  // det + flags
  unsigned int*   sync = (unsigned int*) alloc(sync_bytes);
  unsigned short* E   = (unsigned short*)alloc((size_t)SS * BB * EMBD * 2);      // 4 MB
  unsigned short* Wh  = (unsigned short*)alloc((size_t)2 * 2048 * 512 * 2);      // 4 MB
  unsigned short* Wie = (unsigned short*)alloc((size_t)2 * 2048 * 256 * 2);      // 2 MB
  float*          Bh  = (float*)         alloc((size_t)2 * 2048 * 4);
  unsigned short* Ep  = (unsigned short*)alloc((size_t)2 * 32 * SS * 2048 * 2);  // 67 MB
  unsigned short* H   = (unsigned short*)alloc((size_t)2 * SS * BB * HIDD * 2);  // 16 MB
  unsigned short* LW  = (unsigned short*)alloc((size_t)TPAD * 1024 * 2);
  float*          LB  = (float*)         alloc((size_t)TPAD * 4);
  float*          EM  = (float*)         alloc((size_t)SS * BB * TPAD * 4);      // 1.5 MB
  float*          chain = (float*)       alloc((size_t)BB * 4);

  hipMemsetAsync(sync, 0, sync_bytes, stream);
  k_pack_all<<<dim3(PB_ALL), dim3(256), 0, stream>>>(
      x, emb, E, wih_f, whh_f, b_f, wih_b, whh_b, b_b, Wh, Wie, Bh,
      lin_w, lin_b, LW, LB);
  k_eproj<<<dim3(4096), dim3(256), 0, stream>>>(E, Wie, Bh, Ep);

  void* kargs[] = {&Wh, &Ep, &H, &sync};
  hipLaunchCooperativeKernel((const void*)k_rec, dim3(GRID_REC), dim3(256), kargs, 0, stream);

  k_emis<<<dim3((SS * BB) / 32), dim3(256), 0, stream>>>(H, LW, LB, EM);
  k_crf<<<dim3(BB), dim3(64), 0, stream>>>(tags, start_t, end_t, trans, EM, chain);
  k_fin<<<dim3(1), dim3(64), 0, stream>>>(chain, (float*)d_out);
}